// Round 8
// baseline (444.851 us; speedup 1.0000x reference)
//
#include <hip/hip_runtime.h>

#define H    488
#define HH   (H*H)        // 238144
#define AW   484          // H - 5 + 1
#define KK   6
#define BB   32
#define NB4  (HH/4)       // 59536, exact
#define NBLK 128          // 32 batches x 4 chunks; <= guaranteed-resident capacity (>=256)

// masked load: value is 0 if (i,j) lies inside any of the nr zeroed 5x5 rects
__device__ __forceinline__ float mload(const float* h, int i, int j,
                                       const int* rr, const int* rc, int nr) {
    float v = h[i * H + j];
    for (int t = 0; t < nr; ++t)
        if ((unsigned)(i - rr[t]) < 5u && (unsigned)(j - rc[t]) < 5u) v = 0.0f;
    return v;
}

// single-use grid barrier: device-scope release/acquire around an arrive counter.
// Safe: all NBLK blocks are co-resident (see capacity analysis at launch site).
__device__ __forceinline__ void grid_barrier(int* ctr) {
    __threadfence();                    // release my writes to device scope
    __syncthreads();
    if (threadIdx.x == 0) {
        __hip_atomic_fetch_add(ctr, 1, __ATOMIC_RELEASE, __HIP_MEMORY_SCOPE_AGENT);
        while (__hip_atomic_load(ctr, __ATOMIC_ACQUIRE, __HIP_MEMORY_SCOPE_AGENT) < NBLK)
            __builtin_amdgcn_s_sleep(2);
    }
    __syncthreads();
    __threadfence();                    // acquire: invalidate stale cached lines
}

// ---------------- fused kernel: A (block maxima) -> B (greedy) -> C (scan) -> D (refine) ----------------
__global__ __launch_bounds__(1024) void fused(const float* __restrict__ hm,
                                              double* __restrict__ blockV, int* __restrict__ blockC,
                                              int* __restrict__ rectR, int* __restrict__ rectC,
                                              float* __restrict__ maxv, int* __restrict__ scanres,
                                              int* __restrict__ ctr, float* __restrict__ out) {
    // big LDS union: phase A colsum[16][H] (62464 B)  /  phase B tables (52272 B)
    __shared__ double smem[7808];
    __shared__ int    rrS[KK], rcS[KK];
    __shared__ int    selR, selC;
    __shared__ int    smC[KK];
    __shared__ float  partD[2][KK][2][3];
    __shared__ float  inity[KK], initx[KK];

    int tid  = threadIdx.x;
    int b    = blockIdx.x & 31;          // batch -> XCD locality
    int chunk = blockIdx.x >> 5;         // 0..3
    const float* h = hm + b * HH;
    int wave = tid >> 6, lane = tid & 63;

    // ======== phase A: per-row per-64col-block window maxima ========
    // Association (must match phase B): colsum = ((((v0+v1)+v2)+v3)+v4) f64;
    // horizontal = ((((c0+c1)+c2)+c3)+c4) f64.  blockV[(b*8+p)*AW + r].
    {
        double (*colsum)[H] = (double (*)[H])smem;    // [16][H]
        for (int t = 0; t < 8; ++t) {
            int half = tid >> 9;         // 0..1 (threads 0-511 / 512-1023)
            int j    = tid & 511;
            int g    = chunk * 16 + t * 2 + half;
            if (g < 61 && j < H) {
                int r0 = g * 8;
                float v[12];
                #pragma unroll
                for (int i = 0; i < 12; ++i) {
                    int row = r0 + i;
                    v[i] = (row < H) ? h[row * H + j] : 0.0f;
                }
                #pragma unroll
                for (int w = 0; w < 8; ++w) {
                    double cs = 0.0;
                    #pragma unroll
                    for (int i = 0; i < 5; ++i) cs += (double)v[w + i];
                    colsum[half * 8 + w][j] = cs;
                }
            }
            __syncthreads();
            int rhalf = wave >> 3, w = wave & 7;
            int g2 = chunk * 16 + t * 2 + rhalf;
            if (g2 < 61) {
                int r0 = g2 * 8;
                int nw = (r0 + 8 <= AW) ? 8 : (AW - r0);
                if (w < nw) {
                    int r = r0 + w;
                    double bv[8]; int bc[8];
                    #pragma unroll
                    for (int p = 0; p < 8; ++p) {
                        int c = p * 64 + lane;
                        bv[p] = -1.0; bc[p] = 0x7fffffff;
                        if (c < AW) {
                            double s = 0.0;
                            #pragma unroll
                            for (int k = 0; k < 5; ++k) s += colsum[rhalf * 8 + w][c + k];
                            bv[p] = s; bc[p] = c;
                        }
                    }
                    #pragma unroll
                    for (int off = 32; off; off >>= 1) {
                        #pragma unroll
                        for (int p = 0; p < 8; ++p) {
                            double ov = __shfl_down(bv[p], (unsigned)off);
                            int    oc = __shfl_down(bc[p], (unsigned)off);
                            if (ov > bv[p] || (ov == bv[p] && oc < bc[p])) { bv[p] = ov; bc[p] = oc; }
                        }
                    }
                    if (lane == 0) {
                        #pragma unroll
                        for (int p = 0; p < 8; ++p) {
                            blockV[(b * 8 + p) * AW + r] = bv[p];
                            blockC[(b * 8 + p) * AW + r] = bc[p];
                        }
                    }
                }
            }
            __syncthreads();
        }
    }
    grid_barrier(ctr + 0);

    // ======== phase B: greedy selection (blocks 0..31, one per batch) ========
    if (blockIdx.x < BB) {
        int bb = blockIdx.x;
        const float* hb = hm + bb * HH;
        char* base = (char*)smem;
        double* bV  = (double*)base;                    // 8*AW doubles, conflict-free [p*AW+r]
        int*    bC  = (int*)(base + 30976);
        double* rv  = (double*)(base + 46464);
        int*    rcs = (int*)(base + 50336);

        for (int e = tid; e < 8 * AW; e += 1024) {
            bV[e] = blockV[bb * 8 * AW + e];
            bC[e] = blockC[bb * 8 * AW + e];
        }
        __syncthreads();
        if (tid < AW) {     // row max: ascending p, strict > keeps smallest col on exact ties
            double mv = -2.0; int mc = 0x7fffffff;
            #pragma unroll
            for (int p = 0; p < 8; ++p) {
                double v = bV[p * AW + tid];
                if (v > mv) { mv = v; mc = bC[p * AW + tid]; }
            }
            rv[tid] = mv; rcs[tid] = mc;
        }
        __syncthreads();

        for (int step = 0; step < KK; ++step) {
            if (wave == 0) {
                double bv = -3.0; int br = 0x7fffffff;
                #pragma unroll
                for (int kk = 0; kk < 8; ++kk) {
                    int r = kk * 64 + lane;
                    if (r < AW) {
                        double v = rv[r];
                        if (v > bv || (v == bv && r < br)) { bv = v; br = r; }
                    }
                }
                #pragma unroll
                for (int off = 32; off; off >>= 1) {
                    double ov = __shfl_xor(bv, off);
                    int    orr = __shfl_xor(br, off);
                    if (ov > bv || (ov == bv && orr < br)) { bv = ov; br = orr; }
                }
                int R = br;
                int C = rcs[R];
                if (lane == 0) {
                    rectR[bb * KK + step]   = R;
                    rectC[bb * KK + step]   = C;
                    scanres[bb * KK + step] = 0x7fffffff;
                    rrS[step] = R; rcS[step] = C;
                    selR = R; selC = C;
                }
            }
            __syncthreads();

            int R = selR, C = selC;
            if (wave == 15) {   // 5x5 window max over pre-zeroing state (rects 0..step-1)
                float wv = -1.0f;
                if (lane < 25) wv = mload(hb, R + lane / 5, C + lane % 5, rrS, rcS, step);
                #pragma unroll
                for (int off = 16; off; off >>= 1) wv = fmaxf(wv, __shfl_down(wv, (unsigned)off));
                if (lane == 0) maxv[bb * KK + step] = wv;
            }
            if (step < KK - 1) {
                int rlo = R > 4 ? R - 4 : 0, rhi = R + 4 < AW ? R + 4 : AW - 1;
                int nrows = rhi - rlo + 1;             // <= 9
                if (wave < nrows) {
                    int r = rlo + wave;
                    int cb0 = (C > 4 ? C - 4 : 0) >> 6;
                    int cb1 = (C + 4 < AW ? C + 4 : AW - 1) >> 6;
                    for (int blk = cb0; blk <= cb1; ++blk) {
                        int ac = bC[blk * AW + r];
                        bool dirty = (ac >= C - 4 && ac <= C + 4);  // sums only decrease elsewhere
                        if (dirty) {
                            int jbase = blk * 64;
                            double csA = 0.0, csB = 0.0;
                            int jA = jbase + lane;
                            if (jA < H) {
                                #pragma unroll
                                for (int i = 0; i < 5; ++i) csA += (double)mload(hb, r + i, jA, rrS, rcS, step + 1);
                            }
                            int jB = jbase + 64 + lane;
                            if (lane < 4 && jB < H) {
                                #pragma unroll
                                for (int i = 0; i < 5; ++i) csB += (double)mload(hb, r + i, jB, rrS, rcS, step + 1);
                            }
                            double s = 0.0;
                            #pragma unroll
                            for (int k = 0; k < 5; ++k) {
                                double vA = __shfl_down(csA, (unsigned)k);
                                int srcb = lane + k - 64; if (srcb < 0) srcb = 0;
                                double vB = __shfl(csB, srcb);
                                s += (lane + k < 64) ? vA : vB;
                            }
                            int c = jbase + lane;
                            double bv = -1.0; int bc = 0x7fffffff;
                            if (c < AW) { bv = s; bc = c; }
                            #pragma unroll
                            for (int off = 32; off; off >>= 1) {
                                double ov = __shfl_down(bv, (unsigned)off);
                                int    oc = __shfl_down(bc, (unsigned)off);
                                if (ov > bv || (ov == bv && oc < bc)) { bv = ov; bc = oc; }
                            }
                            if (lane == 0) { bV[blk * AW + r] = bv; bC[blk * AW + r] = bc; }
                        }
                    }
                    if (lane == 0) {    // refresh this row's max
                        double mv = -2.0; int mc = 0x7fffffff;
                        #pragma unroll
                        for (int p = 0; p < 8; ++p) {
                            double v = bV[p * AW + r];
                            if (v > mv) { mv = v; mc = bC[p * AW + r]; }
                        }
                        rv[r] = mv; rcs[r] = mc;
                    }
                }
            }
            __syncthreads();
        }
    }
    grid_barrier(ctr + 1);

    // ======== phase C: fused first-occurrence equality scans (all 128 blocks) ========
    {
        float mv[KK];
        int rr[5], rc[5], lim[KK];
        #pragma unroll
        for (int s = 0; s < KK; ++s) mv[s] = maxv[b * KK + s];
        #pragma unroll
        for (int t = 0; t < 5; ++t) { rr[t] = rectR[b * KK + t]; rc[t] = rectC[b * KK + t]; }
        int limmax = 0;
        #pragma unroll
        for (int s = 0; s < KK; ++s) {
            lim[s] = (rectR[b * KK + s] + 4) * H + rectC[b * KK + s] + 4;
            limmax = lim[s] > limmax ? lim[s] : limmax;
        }
        const float4* h4 = (const float4*)h;
        int local[KK];
        #pragma unroll
        for (int s = 0; s < KK; ++s) local[s] = 0x7fffffff;
        for (int i4 = chunk * 1024 + tid; i4 < NB4; i4 += 4096) {
            if (4 * i4 > limmax) break;          // ascending per-thread index: safe early-out
            float4 v = h4[i4];
            float vs[4] = {v.x, v.y, v.z, v.w};
            #pragma unroll
            for (int e = 0; e < 4; ++e) {
                #pragma unroll
                for (int s = 0; s < KK; ++s) {
                    if (vs[e] == mv[s]) {
                        int n = 4 * i4 + e;
                        if (n <= lim[s]) {
                            int i = n / H, j = n - i * H;
                            bool masked = false;
                            for (int t = 0; t < s; ++t)
                                if ((unsigned)(i - rr[t]) < 5u && (unsigned)(j - rc[t]) < 5u) masked = true;
                            if (!masked && n < local[s]) local[s] = n;
                        }
                    }
                }
            }
        }
        if (tid < KK) smC[tid] = 0x7fffffff;
        __syncthreads();
        #pragma unroll
        for (int s = 0; s < KK; ++s)
            if (local[s] != 0x7fffffff) atomicMin(&smC[s], local[s]);
        __syncthreads();
        if (tid < KK && smC[tid] != 0x7fffffff)
            atomicMin(&scanres[b * KK + tid], smC[tid]);
    }
    grid_barrier(ctr + 2);

    // ======== phase D: refinement + round + confidences (blocks 0..31, 12 working waves) ========
    if (blockIdx.x < BB) {
        int bb = blockIdx.x;
        const float* hb = hm + bb * HH;
        if (tid < KK) {
            int fh = scanres[bb * KK + tid];
            inity[tid] = (float)(fh / H);
            initx[tid] = (float)(fh % H);
        }
        __syncthreads();
        float ys[KK], xs[KK];
        #pragma unroll
        for (int q = 0; q < KK; ++q) { ys[q] = inity[q]; xs[q] = initx[q]; }

        int k = wave >> 1, half = wave & 1;
        for (int it = 0; it < 10; ++it) {
            int pb = it & 1;
            if (wave < 12) {
                float cy = ys[k], cx = xs[k];
                int fy = (int)floorf(cy), fx = (int)floorf(cx);
                int i0 = fy - 12 > 0 ? fy - 12 : 0, i1 = fy + 13 < H - 1 ? fy + 13 : H - 1;
                int j0 = fx - 12 > 0 ? fx - 12 : 0, j1 = fx + 13 < H - 1 ? fx + 13 : H - 1;
                float sy = 0.0f, sx = 0.0f, sw = 0.0f;
                for (int idx = half * 64 + lane; idx < 676; idx += 128) {
                    int di = idx / 26, dj = idx - di * 26;
                    int i = i0 + di, j = j0 + dj;
                    if (i <= i1 && j <= j1) {
                        float hv = hb[i * H + j];
                        float fi = (float)i, fj = (float)j;
                        float d2[KK];
                        #pragma unroll
                        for (int q = 0; q < KK; ++q) {     // fp32-faithful, no FMA contraction
                            float dy = __fsub_rn(fi, ys[q]);
                            float dx = __fsub_rn(fj, xs[q]);
                            d2[q] = __fadd_rn(__fmul_rn(dy, dy), __fmul_rn(dx, dx));
                        }
                        if (d2[k] < 144.0f) {              // == (d < 12), exact by monotonicity
                            float m2 = d2[0];
                            #pragma unroll
                            for (int q = 1; q < KK; ++q) m2 = fminf(m2, d2[q]);
                            float d = fmaxf(__fsqrt_rn(d2[k]), 0.001f);
                            float m = fmaxf(__fsqrt_rn(m2), 0.001f);
                            float w = __fmul_rn(__fdiv_rn(hv, d), __fdiv_rn(m, d));
                            sw += w;
                            sy += w * fi;
                            sx += w * fj;
                        }
                    }
                }
                #pragma unroll
                for (int off = 32; off; off >>= 1) {
                    sy += __shfl_down(sy, (unsigned)off);
                    sx += __shfl_down(sx, (unsigned)off);
                    sw += __shfl_down(sw, (unsigned)off);
                }
                if (lane == 0) { partD[pb][k][half][0] = sy; partD[pb][k][half][1] = sx; partD[pb][k][half][2] = sw; }
            }
            __syncthreads();
            #pragma unroll
            for (int q = 0; q < KK; ++q) {     // every thread combines: identical operands
                float ty = partD[pb][q][0][0] + partD[pb][q][1][0];
                float tx = partD[pb][q][0][1] + partD[pb][q][1][1];
                float tw = partD[pb][q][0][2] + partD[pb][q][1][2];
                ys[q] = ty / tw;
                xs[q] = tx / tw;
            }
        }
        if (tid < KK) {
            int q = tid;
            int iy = __float2int_rn(ys[q]);   // round-half-even, matches jnp.round
            int ix = __float2int_rn(xs[q]);
            out[bb * (KK * 2) + 2 * q]     = (float)iy;
            out[bb * (KK * 2) + 2 * q + 1] = (float)ix;
            int s0 = iy - 2; if (s0 < 0) s0 = 0; if (s0 > H - 4) s0 = H - 4;   // clamped dynamic_slice
            int s1 = ix - 2; if (s1 < 0) s1 = 0; if (s1 > H - 4) s1 = H - 4;
            double cs = 0.0;
            for (int i = 0; i < 4; ++i)
                for (int j = 0; j < 4; ++j) cs += (double)hb[(s0 + i) * H + (s1 + j)];
            out[BB * KK * 2 + bb * KK + q] = (float)cs;
        }
    }
}

// ---------------- launch ----------------
extern "C" void kernel_launch(void* const* d_in, const int* in_sizes, int n_in,
                              void* d_out, int out_size, void* d_ws, size_t ws_size,
                              hipStream_t stream) {
    const float* hm = (const float*)d_in[0];
    float* out = (float*)d_out;

    // ws layout: [0,256): barrier counters (zeroed below); then tables (~1.5 MB)
    int*    ctr     = (int*)d_ws;
    double* blockV  = (double*)((char*)d_ws + 256);  // 32*8*484 f64
    int*    blockC  = (int*)(blockV + BB * 8 * AW);  // 32*8*484 i32
    int*    rectR   = blockC + BB * 8 * AW;          // 32*6
    int*    rectC   = rectR + BB * KK;               // 32*6
    float*  maxv    = (float*)(rectC + BB * KK);     // 32*6
    int*    scanres = (int*)(maxv + BB * KK);        // 32*6

    hipMemsetAsync(d_ws, 0, 256, stream);            // zero barrier counters (capture-safe)

    // Capacity: LDS 62.9KB -> 2 blocks/CU; launch_bounds(1024) -> VGPR<=128 -> >=1 block/CU;
    // worst-case resident capacity 256 >= NBLK=128 -> grid barriers cannot deadlock.
    fused<<<NBLK, 1024, 0, stream>>>(hm, blockV, blockC, rectR, rectC, maxv, scanres, ctr, out);
}

// Round 9
// 419.944 us; speedup vs baseline: 1.0593x; 1.0593x over previous
//
#include <hip/hip_runtime.h>

#define H    488
#define HH   (H*H)        // 238144
#define AW   484          // H - 5 + 1
#define KK   6
#define BB   32
#define NB4  (HH/4)       // 59536, exact
#define GA   16           // K1 blocks per batch
#define GC   8            // K2 blocks per batch
#define CH   ((NB4 + GC - 1) / GC)   // 7442

// masked load: value is 0 if (i,j) lies inside any of the nr zeroed 5x5 rects
__device__ __forceinline__ float mload(const float* h, int i, int j,
                                       const int* rr, const int* rc, int nr) {
    float v = h[i * H + j];
    for (int t = 0; t < nr; ++t)
        if ((unsigned)(i - rr[t]) < 5u && (unsigned)(j - rc[t]) < 5u) v = 0.0f;
    return v;
}

// ---------------- K1: phase A (block maxima) + last-arriver phase B (greedy) ----------------
// Association: colsum = ((((v0+v1)+v2)+v3)+v4) f64; horizontal = ((((c0+c1)+c2)+c3)+c4) f64.
// blockV layout: [(b*8+p)*AW + r] (conflict-free for phase B).
__global__ __launch_bounds__(1024) void k1(const float* __restrict__ hm,
                                           double* __restrict__ blockV, int* __restrict__ blockC,
                                           int* __restrict__ rectR, int* __restrict__ rectC,
                                           float* __restrict__ maxv, int* __restrict__ scanres,
                                           int* __restrict__ doneA) {
    __shared__ double smem[7808];   // A: colsum[16][H] = 62464 B ; B: tables = 52272 B
    __shared__ int    rrS[KK], rcS[KK];
    __shared__ int    selR, selC, lastFlag;
    int tid = threadIdx.x;
    int b   = blockIdx.x & 31;          // batch -> XCD locality
    int blk = blockIdx.x >> 5;          // 0..15
    const float* h = hm + b * HH;
    int wave = tid >> 6, lane = tid & 63;

    // ======== phase A: 4 groups (8 window-rows each), 2 at a time across 1024 threads ========
    {
        double (*colsum)[H] = (double (*)[H])smem;    // [16][H]
        #pragma unroll
        for (int t = 0; t < 2; ++t) {
            int half = tid >> 9;        // 0..1
            int j    = tid & 511;
            int g    = blk * 4 + t * 2 + half;
            if (g < 61 && j < H) {
                int r0 = g * 8;
                float v[12];
                #pragma unroll
                for (int i = 0; i < 12; ++i) {
                    int row = r0 + i;
                    v[i] = (row < H) ? h[row * H + j] : 0.0f;   // coalesced, independent
                }
                #pragma unroll
                for (int w = 0; w < 8; ++w) {
                    double cs = 0.0;
                    #pragma unroll
                    for (int i = 0; i < 5; ++i) cs += (double)v[w + i];
                    colsum[half * 8 + w][j] = cs;
                }
            }
            __syncthreads();
            int rhalf = wave >> 3, w = wave & 7;
            int g2 = blk * 4 + t * 2 + rhalf;
            if (g2 < 61) {
                int r0 = g2 * 8;
                int nw = (r0 + 8 <= AW) ? 8 : (AW - r0);
                if (w < nw) {
                    int r = r0 + w;
                    double bv[8]; int bc[8];
                    #pragma unroll
                    for (int p = 0; p < 8; ++p) {
                        int c = p * 64 + lane;
                        bv[p] = -1.0; bc[p] = 0x7fffffff;
                        if (c < AW) {
                            double s = 0.0;
                            #pragma unroll
                            for (int k = 0; k < 5; ++k) s += colsum[rhalf * 8 + w][c + k];
                            bv[p] = s; bc[p] = c;
                        }
                    }
                    #pragma unroll
                    for (int off = 32; off; off >>= 1) {
                        #pragma unroll
                        for (int p = 0; p < 8; ++p) {
                            double ov = __shfl_down(bv[p], (unsigned)off);
                            int    oc = __shfl_down(bc[p], (unsigned)off);
                            if (ov > bv[p] || (ov == bv[p] && oc < bc[p])) { bv[p] = ov; bc[p] = oc; }
                        }
                    }
                    if (lane == 0) {
                        #pragma unroll
                        for (int p = 0; p < 8; ++p) {
                            blockV[(b * 8 + p) * AW + r] = bv[p];
                            blockC[(b * 8 + p) * AW + r] = bc[p];
                        }
                    }
                }
            }
            __syncthreads();
        }
    }

    // ======== per-batch ticket: last arriver (of 16) runs phase B; no spinning ========
    __threadfence();                    // release my block's blockV/blockC writes
    if (tid == 0) {
        unsigned old = __hip_atomic_fetch_add((unsigned*)&doneA[b], 1u,
                                              __ATOMIC_ACQ_REL, __HIP_MEMORY_SCOPE_AGENT);
        lastFlag = (old == GA - 1);
    }
    __syncthreads();
    if (!lastFlag) return;
    __threadfence();                    // acquire: invalidate stale cache for others' writes

    // ======== phase B: greedy selection (verbatim R6 structure) ========
    {
        char* base = (char*)smem;
        double* bV  = (double*)base;                    // 8*AW doubles [p*AW+r]
        int*    bC  = (int*)(base + 30976);
        double* rv  = (double*)(base + 46464);
        int*    rcs = (int*)(base + 50336);

        for (int e = tid; e < 8 * AW; e += 1024) {
            bV[e] = blockV[b * 8 * AW + e];
            bC[e] = blockC[b * 8 * AW + e];
        }
        __syncthreads();
        if (tid < AW) {     // row max: ascending p, strict > keeps smallest col on exact ties
            double mv = -2.0; int mc = 0x7fffffff;
            #pragma unroll
            for (int p = 0; p < 8; ++p) {
                double v = bV[p * AW + tid];
                if (v > mv) { mv = v; mc = bC[p * AW + tid]; }
            }
            rv[tid] = mv; rcs[tid] = mc;
        }
        __syncthreads();

        for (int step = 0; step < KK; ++step) {
            if (wave == 0) {
                double bv = -3.0; int br = 0x7fffffff;
                #pragma unroll
                for (int kk = 0; kk < 8; ++kk) {
                    int r = kk * 64 + lane;
                    if (r < AW) {
                        double v = rv[r];
                        if (v > bv || (v == bv && r < br)) { bv = v; br = r; }
                    }
                }
                #pragma unroll
                for (int off = 32; off; off >>= 1) {
                    double ov = __shfl_xor(bv, off);
                    int    orr = __shfl_xor(br, off);
                    if (ov > bv || (ov == bv && orr < br)) { bv = ov; br = orr; }
                }
                int R = br;
                int C = rcs[R];
                if (lane == 0) {
                    rectR[b * KK + step]   = R;
                    rectC[b * KK + step]   = C;
                    scanres[b * KK + step] = 0x7fffffff;
                    rrS[step] = R; rcS[step] = C;
                    selR = R; selC = C;
                }
            }
            __syncthreads();

            int R = selR, C = selC;
            if (wave == 15) {   // 5x5 window max over pre-zeroing state (rects 0..step-1)
                float wv = -1.0f;
                if (lane < 25) wv = mload(h, R + lane / 5, C + lane % 5, rrS, rcS, step);
                #pragma unroll
                for (int off = 16; off; off >>= 1) wv = fmaxf(wv, __shfl_down(wv, (unsigned)off));
                if (lane == 0) maxv[b * KK + step] = wv;
            }
            if (step < KK - 1) {
                int rlo = R > 4 ? R - 4 : 0, rhi = R + 4 < AW ? R + 4 : AW - 1;
                int nrows = rhi - rlo + 1;             // <= 9
                if (wave < nrows) {
                    int r = rlo + wave;
                    int cb0 = (C > 4 ? C - 4 : 0) >> 6;
                    int cb1 = (C + 4 < AW ? C + 4 : AW - 1) >> 6;
                    for (int blk2 = cb0; blk2 <= cb1; ++blk2) {
                        int ac = bC[blk2 * AW + r];
                        bool dirty = (ac >= C - 4 && ac <= C + 4);  // sums only decrease elsewhere
                        if (dirty) {
                            int jbase = blk2 * 64;
                            double csA = 0.0, csB = 0.0;
                            int jA = jbase + lane;
                            if (jA < H) {
                                #pragma unroll
                                for (int i = 0; i < 5; ++i) csA += (double)mload(h, r + i, jA, rrS, rcS, step + 1);
                            }
                            int jB = jbase + 64 + lane;
                            if (lane < 4 && jB < H) {
                                #pragma unroll
                                for (int i = 0; i < 5; ++i) csB += (double)mload(h, r + i, jB, rrS, rcS, step + 1);
                            }
                            double s = 0.0;
                            #pragma unroll
                            for (int k = 0; k < 5; ++k) {
                                double vA = __shfl_down(csA, (unsigned)k);
                                int srcb = lane + k - 64; if (srcb < 0) srcb = 0;
                                double vB = __shfl(csB, srcb);
                                s += (lane + k < 64) ? vA : vB;
                            }
                            int c = jbase + lane;
                            double bv = -1.0; int bc = 0x7fffffff;
                            if (c < AW) { bv = s; bc = c; }
                            #pragma unroll
                            for (int off = 32; off; off >>= 1) {
                                double ov = __shfl_down(bv, (unsigned)off);
                                int    oc = __shfl_down(bc, (unsigned)off);
                                if (ov > bv || (ov == bv && oc < bc)) { bv = ov; bc = oc; }
                            }
                            if (lane == 0) { bV[blk2 * AW + r] = bv; bC[blk2 * AW + r] = bc; }
                        }
                    }
                    if (lane == 0) {    // refresh this row's max
                        double mv = -2.0; int mc = 0x7fffffff;
                        #pragma unroll
                        for (int p = 0; p < 8; ++p) {
                            double v = bV[p * AW + r];
                            if (v > mv) { mv = v; mc = bC[p * AW + r]; }
                        }
                        rv[r] = mv; rcs[r] = mc;
                    }
                }
            }
            __syncthreads();
        }
    }
}

// ---------------- K2: phase C (equality scans) + last-arriver phase D (refinement) ----------------
__global__ __launch_bounds__(1024) void k2(const float* __restrict__ hm,
                                           const int* __restrict__ rectR, const int* __restrict__ rectC,
                                           const float* __restrict__ maxv, int* __restrict__ scanres,
                                           int* __restrict__ doneB, float* __restrict__ out) {
    __shared__ int   smC[KK];
    __shared__ int   lastFlag;
    __shared__ float partD[2][KK][2][3];
    __shared__ float inity[KK], initx[KK];
    int tid = threadIdx.x;
    int b     = blockIdx.x & 31;
    int chunk = blockIdx.x >> 5;     // 0..7
    const float* h = hm + b * HH;
    int wave = tid >> 6, lane = tid & 63;

    // ======== phase C: first-occurrence scans over a contiguous chunk ========
    {
        float mv[KK];
        int rr[5], rc[5], lim[KK];
        #pragma unroll
        for (int s = 0; s < KK; ++s) mv[s] = maxv[b * KK + s];
        #pragma unroll
        for (int t = 0; t < 5; ++t) { rr[t] = rectR[b * KK + t]; rc[t] = rectC[b * KK + t]; }
        int limmax = 0;
        #pragma unroll
        for (int s = 0; s < KK; ++s) {
            lim[s] = (rectR[b * KK + s] + 4) * H + rectC[b * KK + s] + 4;  // occurrence exists <= this
            limmax = lim[s] > limmax ? lim[s] : limmax;
        }
        const float4* h4 = (const float4*)h;
        int local[KK];
        #pragma unroll
        for (int s = 0; s < KK; ++s) local[s] = 0x7fffffff;
        int i4end = (chunk + 1) * CH; if (i4end > NB4) i4end = NB4;
        for (int i4 = chunk * CH + tid; i4 < i4end; i4 += 1024) {
            if (4 * i4 > limmax) break;          // ascending per-thread index: safe early-out
            float4 v = h4[i4];
            float vs[4] = {v.x, v.y, v.z, v.w};
            #pragma unroll
            for (int e = 0; e < 4; ++e) {
                #pragma unroll
                for (int s = 0; s < KK; ++s) {
                    if (vs[e] == mv[s]) {
                        int n = 4 * i4 + e;
                        if (n <= lim[s]) {
                            int i = n / H, j = n - i * H;
                            bool masked = false;
                            for (int t = 0; t < s; ++t)
                                if ((unsigned)(i - rr[t]) < 5u && (unsigned)(j - rc[t]) < 5u) masked = true;
                            if (!masked && n < local[s]) local[s] = n;
                        }
                    }
                }
            }
        }
        if (tid < KK) smC[tid] = 0x7fffffff;
        __syncthreads();
        #pragma unroll
        for (int s = 0; s < KK; ++s)
            if (local[s] != 0x7fffffff) atomicMin(&smC[s], local[s]);
        __syncthreads();
        if (tid < KK && smC[tid] != 0x7fffffff)
            atomicMin(&scanres[b * KK + tid], smC[tid]);
        __syncthreads();
    }

    // ======== per-batch ticket: last arriver (of 8) runs phase D; no spinning ========
    __threadfence();
    if (tid == 0) {
        unsigned old = __hip_atomic_fetch_add((unsigned*)&doneB[b], 1u,
                                              __ATOMIC_ACQ_REL, __HIP_MEMORY_SCOPE_AGENT);
        lastFlag = (old == GC - 1);
    }
    __syncthreads();
    if (!lastFlag) return;
    __threadfence();

    // ======== phase D: refinement + round + confidences (12 working waves) ========
    {
        if (tid < KK) {
            int fh = scanres[b * KK + tid];
            inity[tid] = (float)(fh / H);
            initx[tid] = (float)(fh % H);
        }
        __syncthreads();
        float ys[KK], xs[KK];
        #pragma unroll
        for (int q = 0; q < KK; ++q) { ys[q] = inity[q]; xs[q] = initx[q]; }

        int k = wave >> 1, half = wave & 1;
        for (int it = 0; it < 10; ++it) {
            int pb = it & 1;
            if (wave < 12) {
                float cy = ys[k], cx = xs[k];
                int fy = (int)floorf(cy), fx = (int)floorf(cx);
                int i0 = fy - 12 > 0 ? fy - 12 : 0, i1 = fy + 13 < H - 1 ? fy + 13 : H - 1;
                int j0 = fx - 12 > 0 ? fx - 12 : 0, j1 = fx + 13 < H - 1 ? fx + 13 : H - 1;
                float sy = 0.0f, sx = 0.0f, sw = 0.0f;
                for (int idx = half * 64 + lane; idx < 676; idx += 128) {
                    int di = idx / 26, dj = idx - di * 26;
                    int i = i0 + di, j = j0 + dj;
                    if (i <= i1 && j <= j1) {
                        float hv = h[i * H + j];
                        float fi = (float)i, fj = (float)j;
                        float d2[KK];
                        #pragma unroll
                        for (int q = 0; q < KK; ++q) {     // fp32-faithful, no FMA contraction
                            float dy = __fsub_rn(fi, ys[q]);
                            float dx = __fsub_rn(fj, xs[q]);
                            d2[q] = __fadd_rn(__fmul_rn(dy, dy), __fmul_rn(dx, dx));
                        }
                        if (d2[k] < 144.0f) {              // == (d < 12), exact by monotonicity
                            float m2 = d2[0];
                            #pragma unroll
                            for (int q = 1; q < KK; ++q) m2 = fminf(m2, d2[q]);
                            float d = fmaxf(__fsqrt_rn(d2[k]), 0.001f);
                            float m = fmaxf(__fsqrt_rn(m2), 0.001f);
                            float w = __fmul_rn(__fdiv_rn(hv, d), __fdiv_rn(m, d));
                            sw += w;
                            sy += w * fi;
                            sx += w * fj;
                        }
                    }
                }
                #pragma unroll
                for (int off = 32; off; off >>= 1) {
                    sy += __shfl_down(sy, (unsigned)off);
                    sx += __shfl_down(sx, (unsigned)off);
                    sw += __shfl_down(sw, (unsigned)off);
                }
                if (lane == 0) { partD[pb][k][half][0] = sy; partD[pb][k][half][1] = sx; partD[pb][k][half][2] = sw; }
            }
            __syncthreads();
            #pragma unroll
            for (int q = 0; q < KK; ++q) {     // every thread combines: identical operands
                float ty = partD[pb][q][0][0] + partD[pb][q][1][0];
                float tx = partD[pb][q][0][1] + partD[pb][q][1][1];
                float tw = partD[pb][q][0][2] + partD[pb][q][1][2];
                ys[q] = ty / tw;
                xs[q] = tx / tw;
            }
        }
        if (tid < KK) {
            int q = tid;
            int iy = __float2int_rn(ys[q]);   // round-half-even, matches jnp.round
            int ix = __float2int_rn(xs[q]);
            out[b * (KK * 2) + 2 * q]     = (float)iy;
            out[b * (KK * 2) + 2 * q + 1] = (float)ix;
            int s0 = iy - 2; if (s0 < 0) s0 = 0; if (s0 > H - 4) s0 = H - 4;   // clamped dynamic_slice
            int s1 = ix - 2; if (s1 < 0) s1 = 0; if (s1 > H - 4) s1 = H - 4;
            double cs = 0.0;
            for (int i = 0; i < 4; ++i)
                for (int j = 0; j < 4; ++j) cs += (double)h[(s0 + i) * H + (s1 + j)];
            out[BB * KK * 2 + b * KK + q] = (float)cs;
        }
    }
}

// ---------------- launch ----------------
extern "C" void kernel_launch(void* const* d_in, const int* in_sizes, int n_in,
                              void* d_out, int out_size, void* d_ws, size_t ws_size,
                              hipStream_t stream) {
    const float* hm = (const float*)d_in[0];
    float* out = (float*)d_out;

    // ws: [0,128) doneA[32], [128,256) doneB[32], then tables (~1.5 MB)
    int*    doneA   = (int*)d_ws;
    int*    doneB   = doneA + 32;
    double* blockV  = (double*)((char*)d_ws + 256);  // 32*8*484 f64
    int*    blockC  = (int*)(blockV + BB * 8 * AW);  // 32*8*484 i32
    int*    rectR   = blockC + BB * 8 * AW;          // 32*6
    int*    rectC   = rectR + BB * KK;               // 32*6
    float*  maxv    = (float*)(rectC + BB * KK);     // 32*6
    int*    scanres = (int*)(maxv + BB * KK);        // 32*6

    hipMemsetAsync(d_ws, 0, 256, stream);            // zero ticket counters (capture-safe)

    k1<<<BB * GA, 1024, 0, stream>>>(hm, blockV, blockC, rectR, rectC, maxv, scanres, doneA);
    k2<<<BB * GC, 1024, 0, stream>>>(hm, rectR, rectC, maxv, scanres, doneB, out);
}